// Round 2
// baseline (95.469 us; speedup 1.0000x reference)
//
#include <hip/hip_runtime.h>

#define N 1024
#define M 2048
#define P 20
#define ROWS_PER_BLOCK 4
#define THREADS 256

// out layout (float*): matched_points [0,40960) row n at n*40
//                      confidence     [40960,41984) at 40960+n
//                      indices(float) [41984,43008) at 41984+n

__global__ __launch_bounds__(THREADS) void pm_kernel(
    const float* __restrict__ pred, const float* __restrict__ gt,
    float* __restrict__ out)
{
    const int tid  = threadIdx.x;
    const int wrow = tid >> 6;      // one wave per pred row
    const int lane = tid & 63;
    const int n    = blockIdx.x * ROWS_PER_BLOCK + wrow;

    // Load this row's 20 pred points (40 floats) into registers.
    float pr[40];
    const float4* pp = (const float4*)(pred + n * 40);
#pragma unroll
    for (int q = 0; q < 10; ++q) {
        float4 v = pp[q];
        pr[4*q+0] = v.x; pr[4*q+1] = v.y; pr[4*q+2] = v.z; pr[4*q+3] = v.w;
    }

    float bd = 3.4e38f;
    int   bi = 0x7fffffff;
    for (int j = 0; j < M / 64; ++j) {
        const int m = lane + 64 * j;
        const float4* gp = (const float4*)(gt + m * 40);
        float acc = 0.0f;
#pragma unroll
        for (int q = 0; q < 10; ++q) {
            float4 g = gp[q];
            float dx0 = pr[4*q+0] - g.x;
            float dy0 = pr[4*q+1] - g.y;
            float dx1 = pr[4*q+2] - g.z;
            float dy1 = pr[4*q+3] - g.w;
            acc += sqrtf(dx0*dx0 + dy0*dy0);
            acc += sqrtf(dx1*dx1 + dy1*dy1);
        }
        float dist = acc * (1.0f / P);
        if (dist < bd) { bd = dist; bi = m; }   // increasing m -> first occurrence per lane
    }

    // Wave-wide butterfly min+argmin reduce; tie-break = smaller index
    // (matches jnp.argmin first-occurrence semantics).
#pragma unroll
    for (int off = 32; off; off >>= 1) {
        float od = __shfl_xor(bd, off, 64);
        int   oi = __shfl_xor(bi, off, 64);
        if (od < bd || (od == bd && oi < bi)) { bd = od; bi = oi; }
    }

    __shared__ int s_idx[ROWS_PER_BLOCK];
    if (lane == 0) {
        s_idx[wrow] = bi;
        float conf = (bd > 2.0f) ? 0.0f : expf(-bd);
        out[40960 + n] = conf;
        out[41984 + n] = (float)bi;
    }
    __syncthreads();

    // Gather matched gt rows: ROWS_PER_BLOCK * 40 floats per block.
    for (int t = tid; t < ROWS_PER_BLOCK * 40; t += THREADS) {
        const int r = t / 40;
        const int e = t - r * 40;
        const int nn = blockIdx.x * ROWS_PER_BLOCK + r;
        out[nn * 40 + e] = gt[s_idx[r] * 40 + e];
    }
}

extern "C" void kernel_launch(void* const* d_in, const int* in_sizes, int n_in,
                              void* d_out, int out_size, void* d_ws, size_t ws_size,
                              hipStream_t stream) {
    const float* pred = (const float*)d_in[0];   // (1024, 20, 2) fp32
    const float* gt   = (const float*)d_in[1];   // (2048, 20, 2) fp32
    float* out = (float*)d_out;                  // 43008 floats
    (void)in_sizes; (void)n_in; (void)out_size; (void)d_ws; (void)ws_size;
    pm_kernel<<<N / ROWS_PER_BLOCK, THREADS, 0, stream>>>(pred, gt, out);
}